// Round 5
// baseline (78.528 us; speedup 1.0000x reference)
//
#include <hip/hip_runtime.h>
#include <stdint.h>

// quantizer_channel: out[e] = center[ nearest_idx(x[e]) ^ noise_mask(e) ]
//
// nearest_idx == jnp.argmin(|x-center|) reproduced EXACTLY via sorted binary
// search; 15 thresholds bit-bisected in a setup kernel against the reference
// predicate (f32 distances, first-original-index tie-break).
//
// noise bits == jax.random.bernoulli(key(42), .01, [B,C,H,W,4]) under
// partitionable threefry2x32: draw i = w0^w1 of threefry2x32((0,42),(0,i));
// bit = draw < (83887u<<9).   [verified absmax=0 in R1-R4]
//
// R5: threefry pinned via inline asm — 3 VALU/round/chain, in-place, no
// temps; forces the register allocator out of the 12-VGPR remat regime.

#define KS1 42u
#define BERN_LT 42950144u // 83887 << 9

// one threefry round for 4 interleaved chains; sh = 32 - rotl_amount
#define RND(sh)                              \
  "v_add_u32 %0, %0, %4\n"                   \
  "v_add_u32 %1, %1, %5\n"                   \
  "v_add_u32 %2, %2, %6\n"                   \
  "v_add_u32 %3, %3, %7\n"                   \
  "v_alignbit_b32 %4, %4, %4, " sh "\n"      \
  "v_alignbit_b32 %5, %5, %5, " sh "\n"      \
  "v_alignbit_b32 %6, %6, %6, " sh "\n"      \
  "v_alignbit_b32 %7, %7, %7, " sh "\n"      \
  "v_xor_b32 %4, %4, %0\n"                   \
  "v_xor_b32 %5, %5, %1\n"                   \
  "v_xor_b32 %6, %6, %2\n"                   \
  "v_xor_b32 %7, %7, %3\n"

// rotl 13,15,26,6 -> shifts 19,17,6,26 ; rotl 17,29,16,24 -> 15,3,16,8
#define RND_BLK_A RND("19") RND("17") RND("6") RND("26")
#define RND_BLK_B RND("15") RND("3") RND("16") RND("8")

#define INJ_Y0(lit)                          \
  "v_add_u32 %0, " lit ", %0\n"              \
  "v_add_u32 %1, " lit ", %1\n"              \
  "v_add_u32 %2, " lit ", %2\n"              \
  "v_add_u32 %3, " lit ", %3\n"
#define INJ_Y1(lit)                          \
  "v_add_u32 %4, " lit ", %4\n"              \
  "v_add_u32 %5, " lit ", %5\n"              \
  "v_add_u32 %6, " lit ", %6\n"              \
  "v_add_u32 %7, " lit ", %7\n"

// full 20-round threefry2x32 for 4 chains (ks = {0, 42, 0x1BD11BF0})
#define TF_ASM                                        \
  RND_BLK_A INJ_Y0("42")         INJ_Y1("0x1bd11bf1") \
  RND_BLK_B INJ_Y0("0x1bd11bf0") INJ_Y1("2")          \
  RND_BLK_A /* y0 += ks[0]=0 elided */ INJ_Y1("45")   \
  RND_BLK_B INJ_Y0("42")         INJ_Y1("0x1bd11bf4") \
  RND_BLK_A INJ_Y0("0x1bd11bf0") INJ_Y1("5")

// ---------- ordered-float <-> key (monotone total order over floats) ------
__device__ __forceinline__ uint32_t fkey(float f) {
  uint32_t u = __float_as_uint(f);
  return (u & 0x80000000u) ? ~u : (u | 0x80000000u);
}
__device__ __forceinline__ float finv(uint32_t k) {
  uint32_t u = (k & 0x80000000u) ? (k & 0x7fffffffu) : ~k;
  return __uint_as_float(u);
}

// ---------- setup: sort centers, bisect exact cell thresholds -------------
// ws words: [0..14]=T0..T14  [15]=pad  [16]=lut0  [17]=lut1 (4b orig idx)
__global__ void quantizer_setup_kernel(const float* __restrict__ center,
                                       float* __restrict__ ws) {
  const int t = threadIdx.x;
  __shared__ float sval[16];
  __shared__ int   sidx[16];
  if (t < 16) {
    const float ct = center[t];
    int rank = 0;
    for (int j = 0; j < 16; ++j) {
      const float cj = center[j];
      rank += (cj < ct || (cj == ct && j < t)) ? 1 : 0;
    }
    sval[rank] = ct;
    sidx[rank] = t;
  }
  __syncthreads();
  if (t < 15) {
    const float sL = sval[t], sR = sval[t + 1];
    const bool tieLeft = sidx[t] < sidx[t + 1];   // tie -> smaller orig idx
    uint32_t lo = fkey(sL), hi = fkey(sR);        // P(lo)=true, P(hi)=false
    while (hi - lo > 1u) {
      const uint32_t mid = lo + ((hi - lo) >> 1);
      const float xm = finv(mid);
      const float dL = fabsf(xm - sL);            // exactly reference's fl ops
      const float dR = fabsf(xm - sR);
      const bool left = (dL < dR) || (dL == dR && tieLeft);
      if (left) lo = mid; else hi = mid;
    }
    ws[t] = finv(lo);                             // largest float, left wins
  }
  if (t == 15) {
    uint32_t l0 = 0, l1 = 0;
    for (int p = 0; p < 8; ++p) l0 |= ((uint32_t)sidx[p])     << (4 * p);
    for (int p = 0; p < 8; ++p) l1 |= ((uint32_t)sidx[p + 8]) << (4 * p);
    uint32_t* wu = (uint32_t*)ws;
    wu[15] = 0u;
    wu[16] = l0;
    wu[17] = l1;
  }
}

// ---------- main -----------------------------------------------------------
__global__ __launch_bounds__(256) void quantizer_channel_kernel(
    const float* __restrict__ x, const float* __restrict__ center,
    const float* __restrict__ ws, float* __restrict__ out, int n4)
{
  const int t = blockIdx.x * blockDim.x + threadIdx.x;
  if (t >= n4) return;

  const float4 xv = reinterpret_cast<const float4*>(x)[t];

  // thresholds + luts (wave-uniform -> scalar loads)
  const float4* wsf = (const float4*)ws;
  const float4 ta = wsf[0], tb = wsf[1], tc = wsf[2], td = wsf[3];
  const float T0 = ta.x, T1 = ta.y, T2  = ta.z, T3  = ta.w;
  const float T4 = tb.x, T5 = tb.y, T6  = tb.z, T7  = tb.w;
  const float T8 = tc.x, T9 = tc.y, T10 = tc.z, T11 = tc.w;
  const float T12 = td.x, T13 = td.y, T14 = td.z;
  const uint32_t lut0 = ((const uint32_t*)ws)[16];
  const uint32_t lut1 = ((const uint32_t*)ws)[17];

  const float xe[4] = {xv.x, xv.y, xv.z, xv.w};
  float oe[4];
  const uint32_t cb = (uint32_t)t * 16u + KS1;   // counter base + ks1

#pragma unroll
  for (int e = 0; e < 4; ++e) {
    // ---- threefry2x32 x4 chains, counters (0, 16t+4e+j), pinned in asm
    uint32_t a0 = 0u, a1 = 0u, a2 = 0u, a3 = 0u;
    const uint32_t c0 = cb + 4u * (uint32_t)e;
    uint32_t b0 = c0, b1 = c0 + 1u, b2 = c0 + 2u, b3 = c0 + 3u;
    asm(TF_ASM
        : "+v"(a0), "+v"(a1), "+v"(a2), "+v"(a3),
          "+v"(b0), "+v"(b1), "+v"(b2), "+v"(b3));

    uint32_t f = 0u;                              // MSB-first bit pack
    f = f + f + (((a0 ^ b0) < BERN_LT) ? 1u : 0u);
    f = f + f + (((a1 ^ b1) < BERN_LT) ? 1u : 0u);
    f = f + f + (((a2 ^ b2) < BERN_LT) ? 1u : 0u);
    f = f + f + (((a3 ^ b3) < BERN_LT) ? 1u : 0u);

    // ---- exact nearest-center via 4-level select tree over sorted cells
    const float v = xe[e];
    const bool b3_ = v > T7;
    const float s2 = b3_ ? T11 : T3;
    const bool b2_ = v > s2;
    const float s1 = b3_ ? (b2_ ? T13 : T9) : (b2_ ? T5 : T1);
    const bool b1_ = v > s1;
    const float u0 = b1_ ? T2  : T0;
    const float u1 = b1_ ? T6  : T4;
    const float u2 = b1_ ? T10 : T8;
    const float u3 = b1_ ? T14 : T12;
    const float s0 = b3_ ? (b2_ ? u3 : u2) : (b2_ ? u1 : u0);
    const bool b0_ = v > s0;
    const uint32_t shamt = (b2_ ? 16u : 0u) | (b1_ ? 8u : 0u) | (b0_ ? 4u : 0u);
    const uint32_t word = b3_ ? lut1 : lut0;
    const uint32_t best = (word >> shamt) & 15u;  // original center index

    oe[e] = center[best ^ f];                     // 16 floats = 1 cache line
  }

  float4 o4;
  o4.x = oe[0]; o4.y = oe[1]; o4.z = oe[2]; o4.w = oe[3];
  reinterpret_cast<float4*>(out)[t] = o4;
}

extern "C" void kernel_launch(void* const* d_in, const int* in_sizes, int n_in,
                              void* d_out, int out_size, void* d_ws, size_t ws_size,
                              hipStream_t stream)
{
  const float* x      = (const float*)d_in[0];
  const float* center = (const float*)d_in[1];
  float* out          = (float*)d_out;
  float* ws           = (float*)d_ws;

  hipLaunchKernelGGL(quantizer_setup_kernel, dim3(1), dim3(64), 0, stream,
                     center, ws);

  const int N  = in_sizes[0];          // 32*256*32*32 = 8388608, divisible by 4
  const int n4 = N / 4;
  const int block = 256;
  const int grid  = (n4 + block - 1) / block;

  hipLaunchKernelGGL(quantizer_channel_kernel, dim3(grid), dim3(block), 0, stream,
                     x, center, ws, out, n4);
}

// Round 6
// 72.657 us; speedup vs baseline: 1.0808x; 1.0808x over previous
//
#include <hip/hip_runtime.h>
#include <stdint.h>

// quantizer_channel: out[e] = center[ nearest_idx(x[e]) ^ noise_mask(e) ]
//
// nearest_idx == jnp.argmin(|x-center|) reproduced EXACTLY via sorted binary
// search; 15 thresholds bit-bisected in a setup kernel against the reference
// predicate (f32 distances, first-original-index tie-break).
//
// noise bits == jax.random.bernoulli(key(42), .01, [B,C,H,W,4]) under
// partitionable threefry2x32: draw i = w0^w1 of threefry2x32((0,42),(0,i));
// bit = draw < (83887u<<9).   [absmax=0 verified R1-R5]
//
// R6: remove the divergent VMEM gather + LUT bit-twiddling; both become
// ds_bpermute_b32 register-crossbar lookups (idle LDS pipe, zero VMEM).

#define KS1 42u
#define KS2 0x1BD11BF0u   // 0x1BD11BDA ^ 0 ^ 42
#define BERN_LT 42950144u // 83887 << 9

// ---------- ordered-float <-> key (monotone total order over floats) ------
__device__ __forceinline__ uint32_t fkey(float f) {
  uint32_t u = __float_as_uint(f);
  return (u & 0x80000000u) ? ~u : (u | 0x80000000u);
}
__device__ __forceinline__ float finv(uint32_t k) {
  uint32_t u = (k & 0x80000000u) ? (k & 0x7fffffffu) : ~k;
  return __uint_as_float(u);
}

// ---------- setup: sort centers, bisect exact cell thresholds -------------
// ws words: [0..14] = T0..T14 (thresholds, sorted order)
//           [15]    = pad
//           [16..31]= sidx[r] (orig index of sorted rank r, one int each)
__global__ void quantizer_setup_kernel(const float* __restrict__ center,
                                       float* __restrict__ ws) {
  const int t = threadIdx.x;
  __shared__ float sval[16];
  __shared__ int   sidx[16];
  if (t < 16) {
    const float ct = center[t];
    int rank = 0;
    for (int j = 0; j < 16; ++j) {
      const float cj = center[j];
      rank += (cj < ct || (cj == ct && j < t)) ? 1 : 0;
    }
    sval[rank] = ct;
    sidx[rank] = t;
  }
  __syncthreads();
  if (t < 15) {
    const float sL = sval[t], sR = sval[t + 1];
    const bool tieLeft = sidx[t] < sidx[t + 1];   // tie -> smaller orig idx
    uint32_t lo = fkey(sL), hi = fkey(sR);        // P(lo)=true, P(hi)=false
    while (hi - lo > 1u) {
      const uint32_t mid = lo + ((hi - lo) >> 1);
      const float xm = finv(mid);
      const float dL = fabsf(xm - sL);            // exactly reference's fl ops
      const float dR = fabsf(xm - sR);
      const bool left = (dL < dR) || (dL == dR && tieLeft);
      if (left) lo = mid; else hi = mid;
    }
    ws[t] = finv(lo);                             // largest float, left wins
  }
  __syncthreads();
  if (t < 16) {
    ((uint32_t*)ws)[16 + t] = (uint32_t)sidx[t];
    if (t == 15) ((uint32_t*)ws)[15] = 0u;
  }
}

// ---------- threefry helpers ----------------------------------------------
__device__ __forceinline__ uint32_t rotl(uint32_t x, int r) {
  return __builtin_amdgcn_alignbit(x, x, (32 - r) & 31);
}
#define TF_ROUND4(r)                                            \
  { _Pragma("unroll") for (int j = 0; j < 4; ++j) {             \
      y0[j] += y1[j];                                           \
      y1[j] = rotl(y1[j], (r)) ^ y0[j];                         \
  } }
#define TF_INJ4(a, b)                                           \
  { _Pragma("unroll") for (int j = 0; j < 4; ++j) {             \
      y0[j] += (a); y1[j] += (b);                               \
  } }

// ---------- main -----------------------------------------------------------
__global__ __launch_bounds__(256) void quantizer_channel_kernel(
    const float* __restrict__ x, const float* __restrict__ center,
    const float* __restrict__ ws, float* __restrict__ out, int n4)
{
  const int t = blockIdx.x * blockDim.x + threadIdx.x;
  if (t >= n4) return;

  const int lane   = threadIdx.x & 63;
  const int base_b = (lane & 48) << 2;            // bpermute byte base of own 16-group

  // per-lane crossbar tables (replicated every 16 lanes; coalesced 64B line)
  const int ctab = __float_as_int(center[lane & 15]);     // orig-idx -> value
  const int stab = (int)((const uint32_t*)ws)[16 + (lane & 15)]; // rank -> orig idx

  // thresholds (wave-uniform -> scalar regs)
  const float4* wsf = (const float4*)ws;
  const float4 ta = wsf[0], tb = wsf[1], tc = wsf[2], td = wsf[3];
  const float T0 = ta.x, T1 = ta.y, T2  = ta.z, T3  = ta.w;
  const float T4 = tb.x, T5 = tb.y, T6  = tb.z, T7  = tb.w;
  const float T8 = tc.x, T9 = tc.y, T10 = tc.z, T11 = tc.w;
  const float T12 = td.x, T13 = td.y, T14 = td.z;

  const float4 xv = reinterpret_cast<const float4*>(x)[t];
  const float xe[4] = {xv.x, xv.y, xv.z, xv.w};
  float oe[4];
  const uint32_t cb = (uint32_t)t * 16u + KS1;    // counter base + ks1

#pragma unroll
  for (int e = 0; e < 4; ++e) {
    // ---- threefry2x32 x4 chains, counters (0, 16t+4e+j)
    uint32_t y0[4], y1[4];
    const uint32_t c0 = cb + 4u * (uint32_t)e;
#pragma unroll
    for (int j = 0; j < 4; ++j) { y0[j] = 0u; y1[j] = c0 + (uint32_t)j; }
    TF_ROUND4(13) TF_ROUND4(15) TF_ROUND4(26) TF_ROUND4(6)
    TF_INJ4(KS1, KS2 + 1u)
    TF_ROUND4(17) TF_ROUND4(29) TF_ROUND4(16) TF_ROUND4(24)
    TF_INJ4(KS2, 0u + 2u)
    TF_ROUND4(13) TF_ROUND4(15) TF_ROUND4(26) TF_ROUND4(6)
    TF_INJ4(0u, KS1 + 3u)
    TF_ROUND4(17) TF_ROUND4(29) TF_ROUND4(16) TF_ROUND4(24)
    TF_INJ4(KS1, KS2 + 4u)
    TF_ROUND4(13) TF_ROUND4(15) TF_ROUND4(26) TF_ROUND4(6)
    TF_INJ4(KS2, 0u + 5u)

    // ---- flip nibble, MSB-first, ILP pack (cndmask + or3)
    const uint32_t f =
        (((y0[0] ^ y1[0]) < BERN_LT) ? 8u : 0u) |
        (((y0[1] ^ y1[1]) < BERN_LT) ? 4u : 0u) |
        (((y0[2] ^ y1[2]) < BERN_LT) ? 2u : 0u) |
        (((y0[3] ^ y1[3]) < BERN_LT) ? 1u : 0u);

    // ---- exact nearest-center: 4-level select tree over sorted cells
    const float v = xe[e];
    const bool b3_ = v > T7;
    const float s2 = b3_ ? T11 : T3;
    const bool b2_ = v > s2;
    const float s1 = b3_ ? (b2_ ? T13 : T9) : (b2_ ? T5 : T1);
    const bool b1_ = v > s1;
    const float u0 = b1_ ? T2  : T0;
    const float u1 = b1_ ? T6  : T4;
    const float u2 = b1_ ? T10 : T8;
    const float u3 = b1_ ? T14 : T12;
    const float s0 = b3_ ? (b2_ ? u3 : u2) : (b2_ ? u1 : u0);
    const bool b0_ = v > s0;
    const uint32_t cell = (b3_ ? 8u : 0u) | (b2_ ? 4u : 0u) |
                          (b1_ ? 2u : 0u) | (b0_ ? 1u : 0u);

    // rank -> orig index via register crossbar (no VMEM)
    const int best = __builtin_amdgcn_ds_bpermute(base_b + (int)(cell << 2), stab);
    // noisy index -> center value via register crossbar (no VMEM)
    const int fin_addr = base_b + (int)((((uint32_t)best) ^ f) << 2);
    oe[e] = __int_as_float(__builtin_amdgcn_ds_bpermute(fin_addr, ctab));
  }

  float4 o4;
  o4.x = oe[0]; o4.y = oe[1]; o4.z = oe[2]; o4.w = oe[3];
  reinterpret_cast<float4*>(out)[t] = o4;
}

extern "C" void kernel_launch(void* const* d_in, const int* in_sizes, int n_in,
                              void* d_out, int out_size, void* d_ws, size_t ws_size,
                              hipStream_t stream)
{
  const float* x      = (const float*)d_in[0];
  const float* center = (const float*)d_in[1];
  float* out          = (float*)d_out;
  float* ws           = (float*)d_ws;

  hipLaunchKernelGGL(quantizer_setup_kernel, dim3(1), dim3(64), 0, stream,
                     center, ws);

  const int N  = in_sizes[0];          // 32*256*32*32 = 8388608, divisible by 4
  const int n4 = N / 4;
  const int block = 256;
  const int grid  = (n4 + block - 1) / block;

  hipLaunchKernelGGL(quantizer_channel_kernel, dim3(grid), dim3(block), 0, stream,
                     x, center, ws, out, n4);
}